// Round 8
// baseline (90.795 us; speedup 1.0000x reference)
//
#include <hip/hip_runtime.h>

#define B_ 128
#define N1_ 100
#define N2_ 2000
#define NC_ 2100
#define F_ 128
#define NT_ 10
#define L0_ 32
#define L1_ 32
#define L2_ 16

#define NA1 (B_*N1_)          // 12800
#define NA2 (B_*N2_)          // 256000
#define NAC (B_*NC_)          // 268800
#define NATOT (NA1+NA2+NAC)   // 537600
#define NBUCK (NT_*B_)        // 1280
#define CAP_B 512             // per-(type,batch) capacity; mean 233, sigma ~15
#define NFILL (NATOT/256)     // 2100

// prepacked weights per type (half-element offsets):
//   0     : W0 frags, (ks*2+nt)*1024 : hi at +0, lo at +512, index lane*8+e
//   8192  : W1 frags, nt*1024
//   10240 : W2 frag
//   11264 : params f32: b0[32] b1[32] b2[16] ow[16] ob[1]
#define WT_STRIDEH 11520

// workspace layout (bytes)
#define WS_CURSORS 0                                  // 1280*4 = 5120
#define WS_DUMMY   5120                               // 512B scratch "out" for k_main2 (measurement)
#define WS_WPACK   8192
#define WS_LISTS   (WS_WPACK + NT_*WT_STRIDEH*2)      // 238592
#define WS_NEEDED  ((size_t)WS_LISTS + (size_t)NBUCK*CAP_B*4)   // ~2.9 MB

typedef short bf16x8 __attribute__((ext_vector_type(8)));
typedef float f32x4 __attribute__((ext_vector_type(4)));

#define MFMA(a,b,c) __builtin_amdgcn_mfma_f32_16x16x32_bf16((a),(b),(c),0,0,0)

__device__ __forceinline__ unsigned short f2bf(float f){
  unsigned u = __float_as_uint(f);
  unsigned r = (u + 0x7FFFu + ((u >> 16) & 1u)) >> 16;   // RNE
  return (unsigned short)r;
}
__device__ __forceinline__ float bf2f(unsigned short h){
  return __uint_as_float(((unsigned)h) << 16);
}

// 8 packed f32 words -> hi/lo bf16 fragments (truncation split); value args only
// (rule #20: no address-of on register data — r7 scratch-spill lesson).
__device__ __forceinline__ void cvt8u(uint4 a, uint4 b, bf16x8& hi, bf16x8& lo){
  unsigned u[8] = {a.x, a.y, a.z, a.w, b.x, b.y, b.z, b.w};
  union { bf16x8 v; unsigned uu[4]; } H, L;
  #pragma unroll
  for (int i = 0; i < 4; ++i){
    unsigned p = u[2*i], qq = u[2*i+1];
    H.uu[i] = __builtin_amdgcn_perm(qq, p, 0x07060302u);
    unsigned ra = __float_as_uint(__uint_as_float(p)  - __uint_as_float(p  & 0xFFFF0000u));
    unsigned rb = __float_as_uint(__uint_as_float(qq) - __uint_as_float(qq & 0xFFFF0000u));
    L.uu[i] = __builtin_amdgcn_perm(rb, ra, 0x07060302u);
  }
  hi = H.v; lo = L.v;
}

// relu'd f32 -> packed (hi16<<16 | lo16)   [refcheck-verified r4/r5]
__device__ __forceinline__ unsigned packsplit(float h){
  unsigned uh = __float_as_uint(h);
  unsigned tr = uh & 0xFFFF0000u;
  float res = h - __uint_as_float(tr);
  return tr | (__float_as_uint(res) >> 16);
}

__device__ __forceinline__ void unpack8(uint4 p0, uint4 p1, bf16x8& hi, bf16x8& lo){
  unsigned pp[8] = {p0.x, p0.y, p0.z, p0.w, p1.x, p1.y, p1.z, p1.w};
  union { bf16x8 v; unsigned uu[4]; } H, L;
  #pragma unroll
  for (int i = 0; i < 4; ++i){
    H.uu[i] = __builtin_amdgcn_perm(pp[2*i+1], pp[2*i], 0x07060302u);
    L.uu[i] = __builtin_amdgcn_perm(pp[2*i+1], pp[2*i], 0x05040100u);
  }
  hi = H.v; lo = L.v;
}

__device__ __forceinline__ void decode_atom(int g,
    const int* __restrict__ z1, const int* __restrict__ z2, const int* __restrict__ zc,
    int& tensor, int& row, int& b, int& z){
  if (g < NA1){ tensor = 0; row = g; b = g / N1_; z = z1[g]; }
  else if (g < NA1 + NA2){ int i = g - NA1; tensor = 1; row = i; b = i / N2_; z = z2[i]; }
  else { int i = g - NA1 - NA2; tensor = 2; row = i; b = i / NC_; z = zc[i]; }
}

// ---------------- fused fill (blocks 0..NFILL-1) + weight prepack (last NT_ blocks) ----------------
// prep role for t==0 also zeroes out[] (removes the out-memset dispatch; verified r8/r9).

__global__ __launch_bounds__(256) void k_fillprep(
    const int* __restrict__ z1, const int* __restrict__ z2, const int* __restrict__ zc,
    const int* __restrict__ atypes,
    const float* __restrict__ tw0, const float* __restrict__ tb0,
    const float* __restrict__ tw1, const float* __restrict__ tb1,
    const float* __restrict__ tw2, const float* __restrict__ tb2,
    const float* __restrict__ ow, const float* __restrict__ ob,
    unsigned* __restrict__ cursors, unsigned* __restrict__ lists,
    unsigned short* __restrict__ wpack, float* __restrict__ out){
  int tid = threadIdx.x;
  if (blockIdx.x >= NFILL){
    // ---- prep role ----
    int t = blockIdx.x - NFILL;
    unsigned short* base = wpack + (size_t)t * WT_STRIDEH;
    const float* w0 = tw0 + (size_t)t * (F_ * L0_);
    for (int i = tid; i < 4096; i += 256){
      int ks = i >> 10, rem = i & 1023;
      int nt = rem >> 9, rem2 = rem & 511;
      int lane = rem2 >> 3, e = rem2 & 7;
      float f = w0[(ks * 32 + (lane >> 4) * 8 + e) * L0_ + nt * 16 + (lane & 15)];
      unsigned short hi = f2bf(f);
      unsigned short lo = f2bf(f - bf2f(hi));
      int off = (ks * 2 + nt) * 1024 + lane * 8 + e;
      base[off] = hi;
      base[off + 512] = lo;
    }
    const float* w1 = tw1 + (size_t)t * (L0_ * L1_);
    for (int i = tid; i < 1024; i += 256){
      int nt = i >> 9, rem2 = i & 511;
      int lane = rem2 >> 3, e = rem2 & 7;
      float f = w1[((lane >> 4) * 8 + e) * L1_ + nt * 16 + (lane & 15)];
      unsigned short hi = f2bf(f);
      unsigned short lo = f2bf(f - bf2f(hi));
      int off = 8192 + nt * 1024 + lane * 8 + e;
      base[off] = hi;
      base[off + 512] = lo;
    }
    const float* w2 = tw2 + (size_t)t * (L1_ * L2_);
    for (int i = tid; i < 512; i += 256){
      int lane = i >> 3, e = i & 7;
      float f = w2[((lane >> 4) * 8 + e) * L2_ + (lane & 15)];
      unsigned short hi = f2bf(f);
      unsigned short lo = f2bf(f - bf2f(hi));
      int off = 10240 + lane * 8 + e;
      base[off] = hi;
      base[off + 512] = lo;
    }
    float* prm = (float*)(base + 11264);
    if (tid < 32) prm[tid] = tb0[t * L0_ + tid];
    else if (tid < 64) prm[tid] = tb1[t * L1_ + tid - 32];
    else if (tid < 80) prm[tid] = tb2[t * L2_ + tid - 64];
    else if (tid < 96) prm[tid] = ow[t * L2_ + tid - 80];
    else if (tid == 96) prm[96] = ob[t];
    if (t == 0 && tid >= 128 && tid < 128 + B_) out[tid - 128] = 0.0f;
    return;
  }
  // ---- fill role ----
  __shared__ int lut[32];
  __shared__ unsigned lhist[NBUCK];
  __shared__ unsigned lbase[NBUCK];
  for (int i = tid; i < NBUCK; i += 256) lhist[i] = 0u;
  if (tid < 32) lut[tid] = -1;
  __syncthreads();
  if (tid < NT_) lut[atypes[tid] & 31] = tid;
  __syncthreads();
  int g = blockIdx.x * 256 + tid;
  int bucket = -1; unsigned entv = 0u;
  {
    int tensor, row, b, z;
    decode_atom(g, z1, z2, zc, tensor, row, b, z);
    int t = lut[z & 31];
    if (t >= 0){
      bucket = t * B_ + b;
      entv = (unsigned)row | ((unsigned)tensor << 19);
      atomicAdd(&lhist[bucket], 1u);
    }
  }
  __syncthreads();
  for (int i = tid; i < NBUCK; i += 256){
    unsigned c = lhist[i];
    lbase[i] = c ? atomicAdd(&cursors[i], c) : 0u;
    lhist[i] = 0u;                       // reuse as intra-block cursor
  }
  __syncthreads();
  if (bucket >= 0){
    unsigned rank = atomicAdd(&lhist[bucket], 1u) + lbase[bucket];
    if (rank < CAP_B) lists[(size_t)bucket * CAP_B + rank] = entv;
  }
}

// ---------------- main: single-wave MFMA MLP, depth-2 pipelined direct gather ----------------
// r15 k_main = r12/r14 EXACTLY (t-major, fence-free, depth-2; proven 59.0-59.6us).
// MEASUREMENT ROUND: launcher runs k_main TWICE (2nd -> ws scratch out). Delta vs
// 59.6 = k_main2 duration (L3-warm: 153MB gathered set < 256MB L3). Separates
// "HBM-queue-bound" (k_main2 fast) from "structure/latency-bound" (k_main2 ~ k_main1).
// History: depth-2==depth-3==fence-free; b-major swizzle -23%; SORTED lists (perfect
// adjacency) = zero k_main gain (r14) -> order-insensitive; suspect per-CU
// outstanding-miss ceiling x loaded latency. r8 lesson: no multi-wave restructure.
// A-frag: lane l -> m=l&15, k=(l>>4)*8+e.  C/D: n=l&15, m=(l>>4)*4+reg. [refcheck r2-r5]

__global__ __launch_bounds__(64, 2) void k_main(
    const float* __restrict__ f1, const float* __restrict__ f2, const float* __restrict__ fc,
    const unsigned short* __restrict__ wpack,
    const unsigned* __restrict__ cursors, const unsigned* __restrict__ lists,
    float* __restrict__ out){
  int bucket = blockIdx.y;
  int count = (int)cursors[bucket];
  if (count > CAP_B) count = CAP_B;
  int quarter = (count + 3) >> 2;                 // <= 128 atoms (8 tiles)
  int lstart = blockIdx.x * quarter;
  int lend = lstart + quarter; if (lend > count) lend = count;
  int mycount = lend - lstart;
  if (mycount <= 0) return;
  int t = bucket >> 7, b = bucket & 127;
  int lane = threadIdx.x, q = lane >> 4, r16 = lane & 15;

  const unsigned* lst = lists + (size_t)bucket * CAP_B;

  // ---- weights -> registers (once per block) ----
  const unsigned short* wp = wpack + (size_t)t * WT_STRIDEH;
  bf16x8 w0h[8], w0l[8];
  #pragma unroll
  for (int j = 0; j < 8; ++j){
    w0h[j] = *(const bf16x8*)(wp + j * 1024 + lane * 8);
    w0l[j] = *(const bf16x8*)(wp + j * 1024 + 512 + lane * 8);
  }
  bf16x8 w1h[2], w1l[2];
  #pragma unroll
  for (int j = 0; j < 2; ++j){
    w1h[j] = *(const bf16x8*)(wp + 8192 + j * 1024 + lane * 8);
    w1l[j] = *(const bf16x8*)(wp + 8192 + j * 1024 + 512 + lane * 8);
  }
  bf16x8 w2h = *(const bf16x8*)(wp + 10240 + lane * 8);
  bf16x8 w2l = *(const bf16x8*)(wp + 10240 + 512 + lane * 8);
  const float* prm = (const float*)(wp + 11264);
  float b00 = prm[r16],      b01 = prm[16 + r16];
  float b10 = prm[32 + r16], b11 = prm[48 + r16];
  float b2v = prm[64 + r16], owv = prm[80 + r16], obv = prm[96];

  __shared__ unsigned H0[16][44];
  __shared__ unsigned H1[16][44];

  int ntiles = (mycount + 15) >> 4;

  uint4 P0, P1, P2, P3, P4, P5, P6, P7;
  uint4 Q0, Q1, Q2, Q3, Q4, Q5, Q6, Q7;
  bf16x8 aH[4], aL[4];
  float vacc = 0.0f, ssum = 0.0f;

#define FETCHE(j_) lst[min(lstart + (j_) * 16 + r16, lend - 1)]
#define SIGNOF(e_, j_) ((((j_) * 16 + r16) < mycount) ? (((((e_) >> 19) & 3u) == 2u) ? 1.0f : -1.0f) : 0.0f)
#define LOADT(Ej, R0,R1,R2,R3,R4,R5,R6,R7) { \
    int row_ = (int)((Ej) & 0x7FFFFu); \
    int tn_  = (int)(((Ej) >> 19) & 3u); \
    const float* xr_ = ((tn_ == 0) ? f1 : (tn_ == 1) ? f2 : fc) + (size_t)row_ * F_ + q * 8; \
    R0 = *(const uint4*)(xr_);       R1 = *(const uint4*)(xr_ + 4); \
    R2 = *(const uint4*)(xr_ + 32);  R3 = *(const uint4*)(xr_ + 36); \
    R4 = *(const uint4*)(xr_ + 64);  R5 = *(const uint4*)(xr_ + 68); \
    R6 = *(const uint4*)(xr_ + 96);  R7 = *(const uint4*)(xr_ + 100); }

// full 3-layer MLP on fragments in aH/aL; accumulates head into vacc/ssum with SGc.
// FENCE-FREE: compiler-inserted lgkmcnt covers the H0/H1 write->read deps.
#define MLPBODY(SGc) { \
    f32x4 c00 = {b00, b00, b00, b00}; \
    f32x4 c01 = {b01, b01, b01, b01}; \
    _Pragma("unroll") \
    for (int ks = 0; ks < 4; ++ks){ \
      c00 = MFMA(aH[ks], w0h[2*ks],   c00); \
      c00 = MFMA(aL[ks], w0h[2*ks],   c00); \
      c00 = MFMA(aH[ks], w0l[2*ks],   c00); \
      c01 = MFMA(aH[ks], w0h[2*ks+1], c01); \
      c01 = MFMA(aL[ks], w0h[2*ks+1], c01); \
      c01 = MFMA(aH[ks], w0l[2*ks+1], c01); \
    } \
    _Pragma("unroll") \
    for (int reg = 0; reg < 4; ++reg){ \
      H0[4 * q + reg][r16]      = packsplit(fmaxf(c00[reg], 0.0f)); \
      H0[4 * q + reg][16 + r16] = packsplit(fmaxf(c01[reg], 0.0f)); \
    } \
    bf16x8 a1H, a1L; \
    { const unsigned* pr_ = &H0[r16][8 * q]; \
      unpack8(*(const uint4*)pr_, *(const uint4*)(pr_ + 4), a1H, a1L); } \
    f32x4 c10 = {b10, b10, b10, b10}; \
    f32x4 c11 = {b11, b11, b11, b11}; \
    c10 = MFMA(a1H, w1h[0], c10); \
    c10 = MFMA(a1L, w1h[0], c10); \
    c10 = MFMA(a1H, w1l[0], c10); \
    c11 = MFMA(a1H, w1h[1], c11); \
    c11 = MFMA(a1L, w1h[1], c11); \
    c11 = MFMA(a1H, w1l[1], c11); \
    _Pragma("unroll") \
    for (int reg = 0; reg < 4; ++reg){ \
      H1[4 * q + reg][r16]      = packsplit(fmaxf(c10[reg], 0.0f)); \
      H1[4 * q + reg][16 + r16] = packsplit(fmaxf(c11[reg], 0.0f)); \
    } \
    bf16x8 a2H, a2L; \
    { const unsigned* pr_ = &H1[r16][8 * q]; \
      unpack8(*(const uint4*)pr_, *(const uint4*)(pr_ + 4), a2H, a2L); } \
    f32x4 c2 = {b2v, b2v, b2v, b2v}; \
    c2 = MFMA(a2H, w2h, c2); \
    c2 = MFMA(a2L, w2h, c2); \
    c2 = MFMA(a2H, w2l, c2); \
    _Pragma("unroll") \
    for (int reg = 0; reg < 4; ++reg){ \
      float ov = fmaxf(c2[reg], 0.0f) * owv; \
      float sgm = __shfl((SGc), 4 * q + reg, 64); \
      vacc = fmaf(ov, sgm, vacc); \
    } \
    ssum += (SGc); }

  // ---- prologue: tiles 0 and 1 in flight; entries for 2 and 3 prefetched ----
  float sgP, sgQ;
  {
    unsigned e0 = FETCHE(0);
    LOADT(e0, P0, P1, P2, P3, P4, P5, P6, P7);
    sgP = SIGNOF(e0, 0);
  }
  if (ntiles > 1){
    unsigned e1 = FETCHE(1);
    LOADT(e1, Q0, Q1, Q2, Q3, Q4, Q5, Q6, Q7);
    sgQ = SIGNOF(e1, 1);
  } else sgQ = 0.0f;
  unsigned eN = (ntiles > 2) ? FETCHE(2) : 0u;
  unsigned eM = (ntiles > 3) ? FETCHE(3) : 0u;

  for (int it = 0; it < ntiles; it += 2){
    // ---- even tile: consume P, refill P with tile it+2 ----
    {
      float sgc = sgP;
      cvt8u(P0, P1, aH[0], aL[0]);
      cvt8u(P2, P3, aH[1], aL[1]);
      cvt8u(P4, P5, aH[2], aL[2]);
      cvt8u(P6, P7, aH[3], aL[3]);
      if (it + 2 < ntiles){
        LOADT(eN, P0, P1, P2, P3, P4, P5, P6, P7);
        sgP = SIGNOF(eN, it + 2);
        if (it + 4 < ntiles) eN = FETCHE(it + 4);
      }
      MLPBODY(sgc)
    }
    if (it + 1 >= ntiles) break;
    // ---- odd tile: consume Q, refill Q with tile it+3 ----
    {
      float sgc = sgQ;
      cvt8u(Q0, Q1, aH[0], aL[0]);
      cvt8u(Q2, Q3, aH[1], aL[1]);
      cvt8u(Q4, Q5, aH[2], aL[2]);
      cvt8u(Q6, Q7, aH[3], aL[3]);
      if (it + 3 < ntiles){
        LOADT(eM, Q0, Q1, Q2, Q3, Q4, Q5, Q6, Q7);
        sgQ = SIGNOF(eM, it + 3);
        if (it + 5 < ntiles) eM = FETCHE(it + 5);
      }
      MLPBODY(sgc)
    }
  }
#undef FETCHE
#undef SIGNOF
#undef LOADT
#undef MLPBODY

  // fold ob term: Sum_lanes(ssum) = 4 * Sum_atoms(sgn)
  vacc = fmaf(0.25f * obv, ssum, vacc);
  #pragma unroll
  for (int m = 1; m < 64; m <<= 1) vacc += __shfl_xor(vacc, m, 64);
  if (lane == 0) atomicAdd(&out[b], vacc);
}

// ---------------- fallback (ws too small) ----------------

__global__ __launch_bounds__(256) void k_naive(
    const float* __restrict__ f1, const float* __restrict__ f2, const float* __restrict__ fc,
    const int* __restrict__ z1, const int* __restrict__ z2, const int* __restrict__ zc,
    const float* __restrict__ tw0, const float* __restrict__ tb0,
    const float* __restrict__ tw1, const float* __restrict__ tb1,
    const float* __restrict__ tw2, const float* __restrict__ tb2,
    const float* __restrict__ ow, const float* __restrict__ ob,
    const int* __restrict__ atypes, float* __restrict__ out){
  __shared__ int lut[32];
  int tid = threadIdx.x;
  if (tid < 32) lut[tid] = -1;
  __syncthreads();
  if (tid < NT_) lut[atypes[tid] & 31] = tid;
  __syncthreads();
  int g = blockIdx.x * 256 + tid;
  if (g >= NATOT) return;
  int tensor, row, b, z;
  decode_atom(g, z1, z2, zc, tensor, row, b, z);
  int t = lut[z & 31];
  if (t < 0) return;
  const float* x = ((tensor == 0) ? f1 : (tensor == 1) ? f2 : fc) + (size_t)row * F_;
  float h0[L0_];
  #pragma unroll
  for (int j = 0; j < L0_; ++j) h0[j] = tb0[t * L0_ + j];
  for (int k = 0; k < F_; ++k){
    float xx = x[k];
    const float* wr = tw0 + t * (F_ * L0_) + k * L0_;
    #pragma unroll
    for (int j = 0; j < L0_; ++j) h0[j] = fmaf(xx, wr[j], h0[j]);
  }
  #pragma unroll
  for (int j = 0; j < L0_; ++j) h0[j] = fmaxf(h0[j], 0.0f);
  float h1[L1_];
  #pragma unroll
  for (int j = 0; j < L1_; ++j) h1[j] = tb1[t * L1_ + j];
  for (int k = 0; k < L0_; ++k){
    float hh = h0[k];
    const float* wr = tw1 + t * (L1_ * L1_) + k * L1_;
    #pragma unroll
    for (int j = 0; j < L1_; ++j) h1[j] = fmaf(hh, wr[j], h1[j]);
  }
  #pragma unroll
  for (int j = 0; j < L1_; ++j) h1[j] = fmaxf(h1[j], 0.0f);
  float h2[L2_];
  #pragma unroll
  for (int m = 0; m < L2_; ++m) h2[m] = tb2[t * L2_ + m];
  for (int k = 0; k < L1_; ++k){
    float hh = h1[k];
    const float* wr = tw2 + t * (L1_ * L2_) + k * L2_;
    #pragma unroll
    for (int m = 0; m < L2_; ++m) h2[m] = fmaf(hh, wr[m], h2[m]);
  }
  float o = ob[t];
  #pragma unroll
  for (int m = 0; m < L2_; ++m) o += fmaxf(h2[m], 0.0f) * ow[t * L2_ + m];
  float sgn = (tensor == 2) ? 1.0f : -1.0f;
  atomicAdd(&out[b], sgn * o);
}

extern "C" void kernel_launch(void* const* d_in, const int* in_sizes, int n_in,
                              void* d_out, int out_size, void* d_ws, size_t ws_size,
                              hipStream_t stream){
  const float* f1  = (const float*)d_in[0];
  const float* f2  = (const float*)d_in[1];
  const float* fc  = (const float*)d_in[2];
  const int*   z1  = (const int*)d_in[3];
  const int*   z2  = (const int*)d_in[4];
  const int*   zc  = (const int*)d_in[5];
  const float* tw0 = (const float*)d_in[6];
  const float* tb0 = (const float*)d_in[7];
  const float* tw1 = (const float*)d_in[8];
  const float* tb1 = (const float*)d_in[9];
  const float* tw2 = (const float*)d_in[10];
  const float* tb2 = (const float*)d_in[11];
  const float* ow  = (const float*)d_in[12];
  const float* ob  = (const float*)d_in[13];
  const int* atypes = (const int*)d_in[14];
  float* out = (float*)d_out;

  if (ws_size < WS_NEEDED){
    hipMemsetAsync(d_out, 0, B_ * sizeof(float), stream);
    k_naive<<<(NATOT + 255) / 256, 256, 0, stream>>>(
        f1, f2, fc, z1, z2, zc, tw0, tb0, tw1, tb1, tw2, tb2, ow, ob, atypes, out);
    return;
  }

  unsigned* cursors = (unsigned*)((char*)d_ws + WS_CURSORS);
  float* dummy_out  = (float*)((char*)d_ws + WS_DUMMY);
  unsigned short* wpack = (unsigned short*)((char*)d_ws + WS_WPACK);
  unsigned* lists   = (unsigned*)((char*)d_ws + WS_LISTS);

  hipMemsetAsync(cursors, 0, NBUCK * sizeof(unsigned), stream);
  k_fillprep<<<NFILL + NT_, 256, 0, stream>>>(z1, z2, zc, atypes,
      tw0, tb0, tw1, tb1, tw2, tb2, ow, ob, cursors, lists, wpack, out);
  k_main<<<dim3(4, NBUCK), 64, 0, stream>>>(f1, f2, fc, wpack, cursors, lists, out);
  // measurement: second identical k_main into ws scratch (L3-warm); delta vs r12's
  // 59.6us = k_main duration with the gathered set L3-resident.
  k_main<<<dim3(4, NBUCK), 64, 0, stream>>>(f1, f2, fc, wpack, cursors, lists, dummy_out);
}

// Round 9
// 58.664 us; speedup vs baseline: 1.5477x; 1.5477x over previous
//
#include <hip/hip_runtime.h>

#define B_ 128
#define N1_ 100
#define N2_ 2000
#define NC_ 2100
#define F_ 128
#define NT_ 10
#define L0_ 32
#define L1_ 32
#define L2_ 16

#define NA1 (B_*N1_)          // 12800
#define NA2 (B_*N2_)          // 256000
#define NAC (B_*NC_)          // 268800
#define NATOT (NA1+NA2+NAC)   // 537600
#define NBUCK (NT_*B_)        // 1280
#define CAP_B 512             // per-(type,batch) capacity; mean 233, sigma ~15
#define NFILL (NATOT/256)     // 2100

// prepacked weights per type (half-element offsets):
//   0     : W0 frags, (ks*2+nt)*1024 : hi at +0, lo at +512, index lane*8+e
//   8192  : W1 frags, nt*1024
//   10240 : W2 frag
//   11264 : params f32: b0[32] b1[32] b2[16] ow[16] ob[1]
#define WT_STRIDEH 11520

// workspace layout (bytes)
#define WS_CURSORS 0                                  // 1280*4 = 5120
#define WS_WPACK   8192
#define WS_LISTS   (WS_WPACK + NT_*WT_STRIDEH*2)      // 238592
#define WS_NEEDED  ((size_t)WS_LISTS + (size_t)NBUCK*CAP_B*4)   // ~2.9 MB

// ===================== ROOFLINE LEDGER (r8 measurement round) =====================
// k_main L3-warm (153MB resident, r8 double-launch): 31.2 us = 4.9 TB/s effective.
// k_main in-situ: ~45-49 us (~3.3 TB/s). Overhead (memset+fillprep+2 gaps): ~11 us.
// Falsified levers: pipeline depth 2==3 (r10), fence removal neutral (r12),
// b-major schedule locality -23% (r13), PERFECT address sort: zero gain (r14).
// Surviving model: line-request-rate / miss-queue (MSHR) occupancy bound —
// 1.2M independent 128B lines x ~600-900cyc loaded latency saturates per-XCD
// miss queues at ~0.9 lines/cyc/XCD. Warm runs 1.5x faster (shorter latency per
// MSHR slot), exactly matching 3.4 -> 5 TB/s. Bytes are compulsory (f32 inputs,
// contiguous rows, 100% line utilization); streaming-all is worse (275MB + 10x MFMA).
// ==================================================================================

typedef short bf16x8 __attribute__((ext_vector_type(8)));
typedef float f32x4 __attribute__((ext_vector_type(4)));

#define MFMA(a,b,c) __builtin_amdgcn_mfma_f32_16x16x32_bf16((a),(b),(c),0,0,0)

__device__ __forceinline__ unsigned short f2bf(float f){
  unsigned u = __float_as_uint(f);
  unsigned r = (u + 0x7FFFu + ((u >> 16) & 1u)) >> 16;   // RNE
  return (unsigned short)r;
}
__device__ __forceinline__ float bf2f(unsigned short h){
  return __uint_as_float(((unsigned)h) << 16);
}

// 8 packed f32 words -> hi/lo bf16 fragments (truncation split); value args only
// (rule #20: no address-of on register data — r7 scratch-spill lesson).
__device__ __forceinline__ void cvt8u(uint4 a, uint4 b, bf16x8& hi, bf16x8& lo){
  unsigned u[8] = {a.x, a.y, a.z, a.w, b.x, b.y, b.z, b.w};
  union { bf16x8 v; unsigned uu[4]; } H, L;
  #pragma unroll
  for (int i = 0; i < 4; ++i){
    unsigned p = u[2*i], qq = u[2*i+1];
    H.uu[i] = __builtin_amdgcn_perm(qq, p, 0x07060302u);
    unsigned ra = __float_as_uint(__uint_as_float(p)  - __uint_as_float(p  & 0xFFFF0000u));
    unsigned rb = __float_as_uint(__uint_as_float(qq) - __uint_as_float(qq & 0xFFFF0000u));
    L.uu[i] = __builtin_amdgcn_perm(rb, ra, 0x07060302u);
  }
  hi = H.v; lo = L.v;
}

// relu'd f32 -> packed (hi16<<16 | lo16)   [refcheck-verified r4/r5]
__device__ __forceinline__ unsigned packsplit(float h){
  unsigned uh = __float_as_uint(h);
  unsigned tr = uh & 0xFFFF0000u;
  float res = h - __uint_as_float(tr);
  return tr | (__float_as_uint(res) >> 16);
}

__device__ __forceinline__ void unpack8(uint4 p0, uint4 p1, bf16x8& hi, bf16x8& lo){
  unsigned pp[8] = {p0.x, p0.y, p0.z, p0.w, p1.x, p1.y, p1.z, p1.w};
  union { bf16x8 v; unsigned uu[4]; } H, L;
  #pragma unroll
  for (int i = 0; i < 4; ++i){
    H.uu[i] = __builtin_amdgcn_perm(pp[2*i+1], pp[2*i], 0x07060302u);
    L.uu[i] = __builtin_amdgcn_perm(pp[2*i+1], pp[2*i], 0x05040100u);
  }
  hi = H.v; lo = L.v;
}

__device__ __forceinline__ void decode_atom(int g,
    const int* __restrict__ z1, const int* __restrict__ z2, const int* __restrict__ zc,
    int& tensor, int& row, int& b, int& z){
  if (g < NA1){ tensor = 0; row = g; b = g / N1_; z = z1[g]; }
  else if (g < NA1 + NA2){ int i = g - NA1; tensor = 1; row = i; b = i / N2_; z = z2[i]; }
  else { int i = g - NA1 - NA2; tensor = 2; row = i; b = i / NC_; z = zc[i]; }
}

// ---------------- fused fill (blocks 0..NFILL-1) + weight prepack (last NT_ blocks) ----------------
// prep role for t==0 also zeroes out[] (removes the out-memset dispatch; verified r8/r9).

__global__ __launch_bounds__(256) void k_fillprep(
    const int* __restrict__ z1, const int* __restrict__ z2, const int* __restrict__ zc,
    const int* __restrict__ atypes,
    const float* __restrict__ tw0, const float* __restrict__ tb0,
    const float* __restrict__ tw1, const float* __restrict__ tb1,
    const float* __restrict__ tw2, const float* __restrict__ tb2,
    const float* __restrict__ ow, const float* __restrict__ ob,
    unsigned* __restrict__ cursors, unsigned* __restrict__ lists,
    unsigned short* __restrict__ wpack, float* __restrict__ out){
  int tid = threadIdx.x;
  if (blockIdx.x >= NFILL){
    // ---- prep role ----
    int t = blockIdx.x - NFILL;
    unsigned short* base = wpack + (size_t)t * WT_STRIDEH;
    const float* w0 = tw0 + (size_t)t * (F_ * L0_);
    for (int i = tid; i < 4096; i += 256){
      int ks = i >> 10, rem = i & 1023;
      int nt = rem >> 9, rem2 = rem & 511;
      int lane = rem2 >> 3, e = rem2 & 7;
      float f = w0[(ks * 32 + (lane >> 4) * 8 + e) * L0_ + nt * 16 + (lane & 15)];
      unsigned short hi = f2bf(f);
      unsigned short lo = f2bf(f - bf2f(hi));
      int off = (ks * 2 + nt) * 1024 + lane * 8 + e;
      base[off] = hi;
      base[off + 512] = lo;
    }
    const float* w1 = tw1 + (size_t)t * (L0_ * L1_);
    for (int i = tid; i < 1024; i += 256){
      int nt = i >> 9, rem2 = i & 511;
      int lane = rem2 >> 3, e = rem2 & 7;
      float f = w1[((lane >> 4) * 8 + e) * L1_ + nt * 16 + (lane & 15)];
      unsigned short hi = f2bf(f);
      unsigned short lo = f2bf(f - bf2f(hi));
      int off = 8192 + nt * 1024 + lane * 8 + e;
      base[off] = hi;
      base[off + 512] = lo;
    }
    const float* w2 = tw2 + (size_t)t * (L1_ * L2_);
    for (int i = tid; i < 512; i += 256){
      int lane = i >> 3, e = i & 7;
      float f = w2[((lane >> 4) * 8 + e) * L2_ + (lane & 15)];
      unsigned short hi = f2bf(f);
      unsigned short lo = f2bf(f - bf2f(hi));
      int off = 10240 + lane * 8 + e;
      base[off] = hi;
      base[off + 512] = lo;
    }
    float* prm = (float*)(base + 11264);
    if (tid < 32) prm[tid] = tb0[t * L0_ + tid];
    else if (tid < 64) prm[tid] = tb1[t * L1_ + tid - 32];
    else if (tid < 80) prm[tid] = tb2[t * L2_ + tid - 64];
    else if (tid < 96) prm[tid] = ow[t * L2_ + tid - 80];
    else if (tid == 96) prm[96] = ob[t];
    if (t == 0 && tid >= 128 && tid < 128 + B_) out[tid - 128] = 0.0f;
    return;
  }
  // ---- fill role ----
  __shared__ int lut[32];
  __shared__ unsigned lhist[NBUCK];
  __shared__ unsigned lbase[NBUCK];
  for (int i = tid; i < NBUCK; i += 256) lhist[i] = 0u;
  if (tid < 32) lut[tid] = -1;
  __syncthreads();
  if (tid < NT_) lut[atypes[tid] & 31] = tid;
  __syncthreads();
  int g = blockIdx.x * 256 + tid;
  int bucket = -1; unsigned entv = 0u;
  {
    int tensor, row, b, z;
    decode_atom(g, z1, z2, zc, tensor, row, b, z);
    int t = lut[z & 31];
    if (t >= 0){
      bucket = t * B_ + b;
      entv = (unsigned)row | ((unsigned)tensor << 19);
      atomicAdd(&lhist[bucket], 1u);
    }
  }
  __syncthreads();
  for (int i = tid; i < NBUCK; i += 256){
    unsigned c = lhist[i];
    lbase[i] = c ? atomicAdd(&cursors[i], c) : 0u;
    lhist[i] = 0u;                       // reuse as intra-block cursor
  }
  __syncthreads();
  if (bucket >= 0){
    unsigned rank = atomicAdd(&lhist[bucket], 1u) + lbase[bucket];
    if (rank < CAP_B) lists[(size_t)bucket * CAP_B + rank] = entv;
  }
}

// ---------------- main: single-wave MFMA MLP, depth-2 pipelined direct gather ----------------
// r16 = r12 restored EXACTLY (t-major, fence-free, depth-2; proven 59.0-59.6us),
// single launch. See ROOFLINE LEDGER at top for why no further k_main lever exists.
// A-frag: lane l -> m=l&15, k=(l>>4)*8+e.  C/D: n=l&15, m=(l>>4)*4+reg. [refcheck r2-r5]

__global__ __launch_bounds__(64, 2) void k_main(
    const float* __restrict__ f1, const float* __restrict__ f2, const float* __restrict__ fc,
    const unsigned short* __restrict__ wpack,
    const unsigned* __restrict__ cursors, const unsigned* __restrict__ lists,
    float* __restrict__ out){
  int bucket = blockIdx.y;
  int count = (int)cursors[bucket];
  if (count > CAP_B) count = CAP_B;
  int quarter = (count + 3) >> 2;                 // <= 128 atoms (8 tiles)
  int lstart = blockIdx.x * quarter;
  int lend = lstart + quarter; if (lend > count) lend = count;
  int mycount = lend - lstart;
  if (mycount <= 0) return;
  int t = bucket >> 7, b = bucket & 127;
  int lane = threadIdx.x, q = lane >> 4, r16 = lane & 15;

  const unsigned* lst = lists + (size_t)bucket * CAP_B;

  // ---- weights -> registers (once per block) ----
  const unsigned short* wp = wpack + (size_t)t * WT_STRIDEH;
  bf16x8 w0h[8], w0l[8];
  #pragma unroll
  for (int j = 0; j < 8; ++j){
    w0h[j] = *(const bf16x8*)(wp + j * 1024 + lane * 8);
    w0l[j] = *(const bf16x8*)(wp + j * 1024 + 512 + lane * 8);
  }
  bf16x8 w1h[2], w1l[2];
  #pragma unroll
  for (int j = 0; j < 2; ++j){
    w1h[j] = *(const bf16x8*)(wp + 8192 + j * 1024 + lane * 8);
    w1l[j] = *(const bf16x8*)(wp + 8192 + j * 1024 + 512 + lane * 8);
  }
  bf16x8 w2h = *(const bf16x8*)(wp + 10240 + lane * 8);
  bf16x8 w2l = *(const bf16x8*)(wp + 10240 + 512 + lane * 8);
  const float* prm = (const float*)(wp + 11264);
  float b00 = prm[r16],      b01 = prm[16 + r16];
  float b10 = prm[32 + r16], b11 = prm[48 + r16];
  float b2v = prm[64 + r16], owv = prm[80 + r16], obv = prm[96];

  __shared__ unsigned H0[16][44];
  __shared__ unsigned H1[16][44];

  int ntiles = (mycount + 15) >> 4;

  uint4 P0, P1, P2, P3, P4, P5, P6, P7;
  uint4 Q0, Q1, Q2, Q3, Q4, Q5, Q6, Q7;
  bf16x8 aH[4], aL[4];
  float vacc = 0.0f, ssum = 0.0f;

#define FETCHE(j_) lst[min(lstart + (j_) * 16 + r16, lend - 1)]
#define SIGNOF(e_, j_) ((((j_) * 16 + r16) < mycount) ? (((((e_) >> 19) & 3u) == 2u) ? 1.0f : -1.0f) : 0.0f)
#define LOADT(Ej, R0,R1,R2,R3,R4,R5,R6,R7) { \
    int row_ = (int)((Ej) & 0x7FFFFu); \
    int tn_  = (int)(((Ej) >> 19) & 3u); \
    const float* xr_ = ((tn_ == 0) ? f1 : (tn_ == 1) ? f2 : fc) + (size_t)row_ * F_ + q * 8; \
    R0 = *(const uint4*)(xr_);       R1 = *(const uint4*)(xr_ + 4); \
    R2 = *(const uint4*)(xr_ + 32);  R3 = *(const uint4*)(xr_ + 36); \
    R4 = *(const uint4*)(xr_ + 64);  R5 = *(const uint4*)(xr_ + 68); \
    R6 = *(const uint4*)(xr_ + 96);  R7 = *(const uint4*)(xr_ + 100); }

// full 3-layer MLP on fragments in aH/aL; accumulates head into vacc/ssum with SGc.
// FENCE-FREE: compiler-inserted lgkmcnt covers the H0/H1 write->read deps.
#define MLPBODY(SGc) { \
    f32x4 c00 = {b00, b00, b00, b00}; \
    f32x4 c01 = {b01, b01, b01, b01}; \
    _Pragma("unroll") \
    for (int ks = 0; ks < 4; ++ks){ \
      c00 = MFMA(aH[ks], w0h[2*ks],   c00); \
      c00 = MFMA(aL[ks], w0h[2*ks],   c00); \
      c00 = MFMA(aH[ks], w0l[2*ks],   c00); \
      c01 = MFMA(aH[ks], w0h[2*ks+1], c01); \
      c01 = MFMA(aL[ks], w0h[2*ks+1], c01); \
      c01 = MFMA(aH[ks], w0l[2*ks+1], c01); \
    } \
    _Pragma("unroll") \
    for (int reg = 0; reg < 4; ++reg){ \
      H0[4 * q + reg][r16]      = packsplit(fmaxf(c00[reg], 0.0f)); \
      H0[4 * q + reg][16 + r16] = packsplit(fmaxf(c01[reg], 0.0f)); \
    } \
    bf16x8 a1H, a1L; \
    { const unsigned* pr_ = &H0[r16][8 * q]; \
      unpack8(*(const uint4*)pr_, *(const uint4*)(pr_ + 4), a1H, a1L); } \
    f32x4 c10 = {b10, b10, b10, b10}; \
    f32x4 c11 = {b11, b11, b11, b11}; \
    c10 = MFMA(a1H, w1h[0], c10); \
    c10 = MFMA(a1L, w1h[0], c10); \
    c10 = MFMA(a1H, w1l[0], c10); \
    c11 = MFMA(a1H, w1h[1], c11); \
    c11 = MFMA(a1L, w1h[1], c11); \
    c11 = MFMA(a1H, w1l[1], c11); \
    _Pragma("unroll") \
    for (int reg = 0; reg < 4; ++reg){ \
      H1[4 * q + reg][r16]      = packsplit(fmaxf(c10[reg], 0.0f)); \
      H1[4 * q + reg][16 + r16] = packsplit(fmaxf(c11[reg], 0.0f)); \
    } \
    bf16x8 a2H, a2L; \
    { const unsigned* pr_ = &H1[r16][8 * q]; \
      unpack8(*(const uint4*)pr_, *(const uint4*)(pr_ + 4), a2H, a2L); } \
    f32x4 c2 = {b2v, b2v, b2v, b2v}; \
    c2 = MFMA(a2H, w2h, c2); \
    c2 = MFMA(a2L, w2h, c2); \
    c2 = MFMA(a2H, w2l, c2); \
    _Pragma("unroll") \
    for (int reg = 0; reg < 4; ++reg){ \
      float ov = fmaxf(c2[reg], 0.0f) * owv; \
      float sgm = __shfl((SGc), 4 * q + reg, 64); \
      vacc = fmaf(ov, sgm, vacc); \
    } \
    ssum += (SGc); }

  // ---- prologue: tiles 0 and 1 in flight; entries for 2 and 3 prefetched ----
  float sgP, sgQ;
  {
    unsigned e0 = FETCHE(0);
    LOADT(e0, P0, P1, P2, P3, P4, P5, P6, P7);
    sgP = SIGNOF(e0, 0);
  }
  if (ntiles > 1){
    unsigned e1 = FETCHE(1);
    LOADT(e1, Q0, Q1, Q2, Q3, Q4, Q5, Q6, Q7);
    sgQ = SIGNOF(e1, 1);
  } else sgQ = 0.0f;
  unsigned eN = (ntiles > 2) ? FETCHE(2) : 0u;
  unsigned eM = (ntiles > 3) ? FETCHE(3) : 0u;

  for (int it = 0; it < ntiles; it += 2){
    // ---- even tile: consume P, refill P with tile it+2 ----
    {
      float sgc = sgP;
      cvt8u(P0, P1, aH[0], aL[0]);
      cvt8u(P2, P3, aH[1], aL[1]);
      cvt8u(P4, P5, aH[2], aL[2]);
      cvt8u(P6, P7, aH[3], aL[3]);
      if (it + 2 < ntiles){
        LOADT(eN, P0, P1, P2, P3, P4, P5, P6, P7);
        sgP = SIGNOF(eN, it + 2);
        if (it + 4 < ntiles) eN = FETCHE(it + 4);
      }
      MLPBODY(sgc)
    }
    if (it + 1 >= ntiles) break;
    // ---- odd tile: consume Q, refill Q with tile it+3 ----
    {
      float sgc = sgQ;
      cvt8u(Q0, Q1, aH[0], aL[0]);
      cvt8u(Q2, Q3, aH[1], aL[1]);
      cvt8u(Q4, Q5, aH[2], aL[2]);
      cvt8u(Q6, Q7, aH[3], aL[3]);
      if (it + 3 < ntiles){
        LOADT(eM, Q0, Q1, Q2, Q3, Q4, Q5, Q6, Q7);
        sgQ = SIGNOF(eM, it + 3);
        if (it + 5 < ntiles) eM = FETCHE(it + 5);
      }
      MLPBODY(sgc)
    }
  }
#undef FETCHE
#undef SIGNOF
#undef LOADT
#undef MLPBODY

  // fold ob term: Sum_lanes(ssum) = 4 * Sum_atoms(sgn)
  vacc = fmaf(0.25f * obv, ssum, vacc);
  #pragma unroll
  for (int m = 1; m < 64; m <<= 1) vacc += __shfl_xor(vacc, m, 64);
  if (lane == 0) atomicAdd(&out[b], vacc);
}

// ---------------- fallback (ws too small) ----------------

__global__ __launch_bounds__(256) void k_naive(
    const float* __restrict__ f1, const float* __restrict__ f2, const float* __restrict__ fc,
    const int* __restrict__ z1, const int* __restrict__ z2, const int* __restrict__ zc,
    const float* __restrict__ tw0, const float* __restrict__ tb0,
    const float* __restrict__ tw1, const float* __restrict__ tb1,
    const float* __restrict__ tw2, const float* __restrict__ tb2,
    const float* __restrict__ ow, const float* __restrict__ ob,
    const int* __restrict__ atypes, float* __restrict__ out){
  __shared__ int lut[32];
  int tid = threadIdx.x;
  if (tid < 32) lut[tid] = -1;
  __syncthreads();
  if (tid < NT_) lut[atypes[tid] & 31] = tid;
  __syncthreads();
  int g = blockIdx.x * 256 + tid;
  if (g >= NATOT) return;
  int tensor, row, b, z;
  decode_atom(g, z1, z2, zc, tensor, row, b, z);
  int t = lut[z & 31];
  if (t < 0) return;
  const float* x = ((tensor == 0) ? f1 : (tensor == 1) ? f2 : fc) + (size_t)row * F_;
  float h0[L0_];
  #pragma unroll
  for (int j = 0; j < L0_; ++j) h0[j] = tb0[t * L0_ + j];
  for (int k = 0; k < F_; ++k){
    float xx = x[k];
    const float* wr = tw0 + t * (F_ * L0_) + k * L0_;
    #pragma unroll
    for (int j = 0; j < L0_; ++j) h0[j] = fmaf(xx, wr[j], h0[j]);
  }
  #pragma unroll
  for (int j = 0; j < L0_; ++j) h0[j] = fmaxf(h0[j], 0.0f);
  float h1[L1_];
  #pragma unroll
  for (int j = 0; j < L1_; ++j) h1[j] = tb1[t * L1_ + j];
  for (int k = 0; k < L0_; ++k){
    float hh = h0[k];
    const float* wr = tw1 + t * (L1_ * L1_) + k * L1_;
    #pragma unroll
    for (int j = 0; j < L1_; ++j) h1[j] = fmaf(hh, wr[j], h1[j]);
  }
  #pragma unroll
  for (int j = 0; j < L1_; ++j) h1[j] = fmaxf(h1[j], 0.0f);
  float h2[L2_];
  #pragma unroll
  for (int m = 0; m < L2_; ++m) h2[m] = tb2[t * L2_ + m];
  for (int k = 0; k < L1_; ++k){
    float hh = h1[k];
    const float* wr = tw2 + t * (L1_ * L2_) + k * L2_;
    #pragma unroll
    for (int m = 0; m < L2_; ++m) h2[m] = fmaf(hh, wr[m], h2[m]);
  }
  float o = ob[t];
  #pragma unroll
  for (int m = 0; m < L2_; ++m) o += fmaxf(h2[m], 0.0f) * ow[t * L2_ + m];
  float sgn = (tensor == 2) ? 1.0f : -1.0f;
  atomicAdd(&out[b], sgn * o);
}

extern "C" void kernel_launch(void* const* d_in, const int* in_sizes, int n_in,
                              void* d_out, int out_size, void* d_ws, size_t ws_size,
                              hipStream_t stream){
  const float* f1  = (const float*)d_in[0];
  const float* f2  = (const float*)d_in[1];
  const float* fc  = (const float*)d_in[2];
  const int*   z1  = (const int*)d_in[3];
  const int*   z2  = (const int*)d_in[4];
  const int*   zc  = (const int*)d_in[5];
  const float* tw0 = (const float*)d_in[6];
  const float* tb0 = (const float*)d_in[7];
  const float* tw1 = (const float*)d_in[8];
  const float* tb1 = (const float*)d_in[9];
  const float* tw2 = (const float*)d_in[10];
  const float* tb2 = (const float*)d_in[11];
  const float* ow  = (const float*)d_in[12];
  const float* ob  = (const float*)d_in[13];
  const int* atypes = (const int*)d_in[14];
  float* out = (float*)d_out;

  if (ws_size < WS_NEEDED){
    hipMemsetAsync(d_out, 0, B_ * sizeof(float), stream);
    k_naive<<<(NATOT + 255) / 256, 256, 0, stream>>>(
        f1, f2, fc, z1, z2, zc, tw0, tb0, tw1, tb1, tw2, tb2, ow, ob, atypes, out);
    return;
  }

  unsigned* cursors = (unsigned*)((char*)d_ws + WS_CURSORS);
  unsigned short* wpack = (unsigned short*)((char*)d_ws + WS_WPACK);
  unsigned* lists   = (unsigned*)((char*)d_ws + WS_LISTS);

  hipMemsetAsync(cursors, 0, NBUCK * sizeof(unsigned), stream);
  k_fillprep<<<NFILL + NT_, 256, 0, stream>>>(z1, z2, zc, atypes,
      tw0, tb0, tw1, tb1, tw2, tb2, ow, ob, cursors, lists, wpack, out);
  k_main<<<dim3(4, NBUCK), 64, 0, stream>>>(f1, f2, fc, wpack, cursors, lists, out);
}